// Round 3
// baseline (371.706 us; speedup 1.0000x reference)
//
#include <hip/hip_runtime.h>

#define N_NODES 10000
#define N_EDGES 320000
#define OBS_DIM 30
#define ACT_DIM 4
#define HID 128

// ---------------- zero scratch ----------------

__global__ __launch_bounds__(256) void k_zero(int* __restrict__ cnt, int* __restrict__ fill) {
    int i = blockIdx.x * blockDim.x + threadIdx.x;
    if (i < N_NODES) {
        cnt[i] = 0;
        fill[i] = 0;
    }
}

// ---------------- CSR build ----------------

__global__ void k_hist(const int* __restrict__ dst, int* __restrict__ cnt) {
    int e = blockIdx.x * blockDim.x + threadIdx.x;
    if (e < N_EDGES) atomicAdd(&cnt[dst[e]], 1);
}

// Single-block exclusive scan over cnt -> rowptr; also dis[i] = 1/sqrt(cnt[i]+1)
__global__ __launch_bounds__(256) void k_scan(const int* __restrict__ cnt,
                                              int* __restrict__ rowptr,
                                              float* __restrict__ dis) {
    __shared__ int s[256];
    int t = threadIdx.x;
    const int CH = 40;  // 250*40 = 10000 exactly; threads 250..255 idle
    int beg = t * CH;
    bool active = beg < N_NODES;
    int vals[CH];
    int sum = 0;
    if (active) {
        const int4* cp = (const int4*)(cnt + beg);
#pragma unroll
        for (int v = 0; v < CH / 4; ++v) {
            int4 q = cp[v];
            vals[4 * v + 0] = q.x;
            vals[4 * v + 1] = q.y;
            vals[4 * v + 2] = q.z;
            vals[4 * v + 3] = q.w;
        }
#pragma unroll
        for (int i = 0; i < CH; ++i) sum += vals[i];
    }
    s[t] = sum;
    __syncthreads();
    for (int off = 1; off < 256; off <<= 1) {
        int v = (t >= off) ? s[t - off] : 0;
        __syncthreads();
        s[t] += v;
        __syncthreads();
    }
    if (active) {
        int run = s[t] - sum;
        int rp[CH];
        float dv[CH];
#pragma unroll
        for (int i = 0; i < CH; ++i) {
            rp[i] = run;
            int c = vals[i];
            dv[i] = rsqrtf((float)(c + 1));  // +1 for self-loop
            run += c;
        }
        int4* rpp = (int4*)(rowptr + beg);
        float4* dp = (float4*)(dis + beg);
#pragma unroll
        for (int v = 0; v < CH / 4; ++v) {
            rpp[v] = make_int4(rp[4 * v], rp[4 * v + 1], rp[4 * v + 2], rp[4 * v + 3]);
            dp[v] = make_float4(dv[4 * v], dv[4 * v + 1], dv[4 * v + 2], dv[4 * v + 3]);
        }
    }
    if (t == 255) rowptr[N_NODES] = s[255];
}

__global__ void k_fill(const int* __restrict__ src, const int* __restrict__ dst,
                       const int* __restrict__ rowptr, int* __restrict__ fill,
                       int* __restrict__ col) {
    int e = blockIdx.x * blockDim.x + threadIdx.x;
    if (e < N_EDGES) {
        int d = dst[e];
        int p = atomicAdd(&fill[d], 1);
        col[rowptr[d] + p] = src[e];
    }
}

// ---------------- GEMM1: y = dis[i] * (concat(obs,act) @ W)  [10000x34 @ 34x128]

__global__ __launch_bounds__(256) void k_gemm1(const float* __restrict__ obs,
                                               const float* __restrict__ act,
                                               const float* __restrict__ W,
                                               const float* __restrict__ dis,
                                               float* __restrict__ y) {
    __shared__ float xs[16 * 34];
    __shared__ float ws[34 * 128];
    int t = threadIdx.x;
    int row0 = blockIdx.x * 16;  // 625 * 16 = 10000
    for (int i = t; i < 16 * 34; i += 256) {
        int r = i / 34, k = i % 34;
        int row = row0 + r;
        xs[i] = (k < OBS_DIM) ? obs[row * OBS_DIM + k]
                              : act[row * ACT_DIM + (k - OBS_DIM)];
    }
    {
        float4* wsp = (float4*)ws;
        const float4* Wp = (const float4*)W;
        for (int i = t; i < 34 * 128 / 4; i += 256) wsp[i] = Wp[i];
    }
    __syncthreads();
    int c = t & 127, half = t >> 7;
    float acc[8] = {0, 0, 0, 0, 0, 0, 0, 0};
    for (int k = 0; k < 34; ++k) {
        float wv = ws[k * 128 + c];
#pragma unroll
        for (int r = 0; r < 8; ++r) acc[r] += xs[(half * 8 + r) * 34 + k] * wv;
    }
#pragma unroll
    for (int r = 0; r < 8; ++r) {
        int row = row0 + half * 8 + r;
        y[row * HID + c] = dis[row] * acc[r];
    }
}

// ---------------- fused agg + GEMV: y2 = dis * (relu(dis*(sum_N y1 + y1) + b1) @ W2)
// 1250 blocks x 8 nodes; 4 waves, each wave gathers 2 nodes into LDS, then block GEMM.

__global__ __launch_bounds__(256) void k_agg_gemv(const float2* __restrict__ y,
                                                  const int* __restrict__ rowptr,
                                                  const int* __restrict__ col,
                                                  const float* __restrict__ dis,
                                                  const float2* __restrict__ bias,
                                                  const float* __restrict__ W,
                                                  float* __restrict__ y2) {
    __shared__ float hs[8 * 128];
    __shared__ float ws[32 * 128];
    int t = threadIdx.x;
    int wave = t >> 6, lane = t & 63;
    int row0 = blockIdx.x * 8;
#pragma unroll
    for (int i = 0; i < 2; ++i) {
        int loc = wave * 2 + i;
        int node = row0 + loc;
        int beg = rowptr[node], end = rowptr[node + 1];
        float2 a = y[node * 64 + lane];
        int e = beg;
        for (; e + 4 <= end; e += 4) {
            int j0 = col[e], j1 = col[e + 1], j2 = col[e + 2], j3 = col[e + 3];
            float2 v0 = y[j0 * 64 + lane];
            float2 v1 = y[j1 * 64 + lane];
            float2 v2 = y[j2 * 64 + lane];
            float2 v3 = y[j3 * 64 + lane];
            a.x += (v0.x + v1.x) + (v2.x + v3.x);
            a.y += (v0.y + v1.y) + (v2.y + v3.y);
        }
        for (; e < end; ++e) {
            float2 v = y[col[e] * 64 + lane];
            a.x += v.x;
            a.y += v.y;
        }
        float di = dis[node];
        float2 b = bias[lane];
        float2 h;
        h.x = fmaxf(di * a.x + b.x, 0.0f);
        h.y = fmaxf(di * a.y + b.y, 0.0f);
        *(float2*)&hs[loc * 128 + 2 * lane] = h;
    }
    int c = t & 127, half = t >> 7;
    float acc[4] = {0, 0, 0, 0};
    for (int ch = 0; ch < 4; ++ch) {
        __syncthreads();  // first iter: also guards hs completion
        {
            float4* wsp = (float4*)ws;
            const float4* Wp = (const float4*)(W + ch * 4096);
            for (int i = t; i < 1024; i += 256) wsp[i] = Wp[i];
        }
        __syncthreads();
        for (int k = 0; k < 32; ++k) {
            float wv = ws[k * 128 + c];
#pragma unroll
            for (int r = 0; r < 4; ++r)
                acc[r] += hs[(half * 4 + r) * 128 + ch * 32 + k] * wv;
        }
    }
#pragma unroll
    for (int r = 0; r < 4; ++r) {
        int row = row0 + half * 4 + r;
        y2[row * 128 + c] = dis[row] * acc[r];
    }
}

// ---------------- fused agg + dual heads:
// h2 = relu(dis*(sum_N y2 + y2) + b2); q = relu(h2@Wa+Ba) . wb + bb

__global__ __launch_bounds__(256) void k_agg_heads(const float2* __restrict__ y,
                                                   const int* __restrict__ rowptr,
                                                   const int* __restrict__ col,
                                                   const float* __restrict__ dis,
                                                   const float2* __restrict__ bias,
                                                   const float* __restrict__ W1, const float* __restrict__ B1,
                                                   const float* __restrict__ w1b, const float* __restrict__ b1b,
                                                   const float* __restrict__ W2, const float* __restrict__ B2,
                                                   const float* __restrict__ w2b, const float* __restrict__ b2b,
                                                   float* __restrict__ q1, float* __restrict__ q2) {
    __shared__ float hs[8 * 128];
    __shared__ float w1s[32 * 128];
    __shared__ float w2s[32 * 128];
    __shared__ float part1[4][4];
    __shared__ float part2[4][4];
    int t = threadIdx.x;
    int wave = t >> 6, lane = t & 63;
    int row0 = blockIdx.x * 8;
#pragma unroll
    for (int i = 0; i < 2; ++i) {
        int loc = wave * 2 + i;
        int node = row0 + loc;
        int beg = rowptr[node], end = rowptr[node + 1];
        float2 a = y[node * 64 + lane];
        int e = beg;
        for (; e + 4 <= end; e += 4) {
            int j0 = col[e], j1 = col[e + 1], j2 = col[e + 2], j3 = col[e + 3];
            float2 v0 = y[j0 * 64 + lane];
            float2 v1 = y[j1 * 64 + lane];
            float2 v2 = y[j2 * 64 + lane];
            float2 v3 = y[j3 * 64 + lane];
            a.x += (v0.x + v1.x) + (v2.x + v3.x);
            a.y += (v0.y + v1.y) + (v2.y + v3.y);
        }
        for (; e < end; ++e) {
            float2 v = y[col[e] * 64 + lane];
            a.x += v.x;
            a.y += v.y;
        }
        float di = dis[node];
        float2 b = bias[lane];
        float2 h;
        h.x = fmaxf(di * a.x + b.x, 0.0f);
        h.y = fmaxf(di * a.y + b.y, 0.0f);
        *(float2*)&hs[loc * 128 + 2 * lane] = h;
    }
    int c = t & 127, half = t >> 7;
    float a1[4] = {0, 0, 0, 0};
    float a2[4] = {0, 0, 0, 0};
    for (int ch = 0; ch < 4; ++ch) {
        __syncthreads();  // first iter: also guards hs completion
        {
            float4* w1p = (float4*)w1s;
            float4* w2p = (float4*)w2s;
            const float4* W1p = (const float4*)(W1 + ch * 4096);
            const float4* W2p = (const float4*)(W2 + ch * 4096);
            for (int i = t; i < 1024; i += 256) {
                w1p[i] = W1p[i];
                w2p[i] = W2p[i];
            }
        }
        __syncthreads();
        for (int k = 0; k < 32; ++k) {
            float wv1 = w1s[k * 128 + c];
            float wv2 = w2s[k * 128 + c];
#pragma unroll
            for (int r = 0; r < 4; ++r) {
                float xv = hs[(half * 4 + r) * 128 + ch * 32 + k];
                a1[r] += xv * wv1;
                a2[r] += xv * wv2;
            }
        }
    }
    float bb1 = B1[c], bb2 = B2[c];
    float v1 = w1b[c], v2 = w2b[c];
    float s1[4], s2[4];
#pragma unroll
    for (int r = 0; r < 4; ++r) {
        float h1 = fmaxf(a1[r] + bb1, 0.0f);
        float h2 = fmaxf(a2[r] + bb2, 0.0f);
        s1[r] = h1 * v1;
        s2[r] = h2 * v2;
    }
#pragma unroll
    for (int off = 1; off < 64; off <<= 1) {
#pragma unroll
        for (int r = 0; r < 4; ++r) {
            s1[r] += __shfl_xor(s1[r], off);
            s2[r] += __shfl_xor(s2[r], off);
        }
    }
    if (lane == 0) {
#pragma unroll
        for (int r = 0; r < 4; ++r) {
            part1[wave][r] = s1[r];
            part2[wave][r] = s2[r];
        }
    }
    __syncthreads();
    if (t < 8) {
        int hf = t >> 2, r = t & 3;
        int row = row0 + t;
        q1[row] = part1[hf * 2][r] + part1[hf * 2 + 1][r] + b1b[0];
        q2[row] = part2[hf * 2][r] + part2[hf * 2 + 1][r] + b2b[0];
    }
}

extern "C" void kernel_launch(void* const* d_in, const int* in_sizes, int n_in,
                              void* d_out, int out_size, void* d_ws, size_t ws_size,
                              hipStream_t stream) {
    (void)in_sizes; (void)n_in; (void)out_size; (void)ws_size;
    const float* obs  = (const float*)d_in[0];
    const float* act  = (const float*)d_in[1];
    const int*   ei   = (const int*)d_in[2];
    const int*   src  = ei;
    const int*   dst  = ei + N_EDGES;
    const float* w_g1 = (const float*)d_in[3];
    const float* b_g1 = (const float*)d_in[4];
    const float* w_g2 = (const float*)d_in[5];
    const float* b_g2 = (const float*)d_in[6];
    const float* w_q1a = (const float*)d_in[7];
    const float* b_q1a = (const float*)d_in[8];
    const float* w_q1b = (const float*)d_in[9];
    const float* b_q1b = (const float*)d_in[10];
    const float* w_q2a = (const float*)d_in[11];
    const float* b_q2a = (const float*)d_in[12];
    const float* w_q2b = (const float*)d_in[13];
    const float* b_q2b = (const float*)d_in[14];
    float* out = (float*)d_out;

    char* ws = (char*)d_ws;
    size_t off = 0;
    auto alloc = [&](size_t bytes) {
        void* p = ws + off;
        off = (off + bytes + 255) & ~(size_t)255;
        return p;
    };
    int*   cnt    = (int*)alloc(N_NODES * 4);
    int*   fill   = (int*)alloc(N_NODES * 4);
    int*   rowptr = (int*)alloc((N_NODES + 1) * 4);
    float* dis    = (float*)alloc(N_NODES * 4);
    int*   col    = (int*)alloc((size_t)N_EDGES * 4);
    float* buf0   = (float*)alloc((size_t)N_NODES * HID * 4);
    float* buf1   = (float*)alloc((size_t)N_NODES * HID * 4);

    k_zero<<<(N_NODES + 255) / 256, 256, 0, stream>>>(cnt, fill);
    k_hist<<<(N_EDGES + 255) / 256, 256, 0, stream>>>(dst, cnt);
    k_scan<<<1, 256, 0, stream>>>(cnt, rowptr, dis);
    k_fill<<<(N_EDGES + 255) / 256, 256, 0, stream>>>(src, dst, rowptr, fill, col);

    k_gemm1<<<625, 256, 0, stream>>>(obs, act, w_g1, dis, buf0);
    k_agg_gemv<<<1250, 256, 0, stream>>>((const float2*)buf0, rowptr, col, dis,
                                         (const float2*)b_g1, w_g2, buf1);
    k_agg_heads<<<1250, 256, 0, stream>>>((const float2*)buf1, rowptr, col, dis,
                                          (const float2*)b_g2,
                                          w_q1a, b_q1a, w_q1b, b_q1b,
                                          w_q2a, b_q2a, w_q2b, b_q2b,
                                          out, out + N_NODES);
}

// Round 4
// 144.731 us; speedup vs baseline: 2.5683x; 2.5683x over previous
//
#include <hip/hip_runtime.h>

#define N_NODES 10000
#define N_EDGES 320000
#define OBS_DIM 30
#define ACT_DIM 4
#define HID 128

// ---------------- zero scratch ----------------

__global__ __launch_bounds__(256) void k_zero(int* __restrict__ cnt, int* __restrict__ fill) {
    int i = blockIdx.x * blockDim.x + threadIdx.x;
    if (i < N_NODES) {
        cnt[i] = 0;
        fill[i] = 0;
    }
}

// ---------------- CSR build ----------------

__global__ void k_hist(const int4* __restrict__ dst4, int* __restrict__ cnt) {
    int i = blockIdx.x * blockDim.x + threadIdx.x;
    if (i < N_EDGES / 4) {
        int4 d = dst4[i];
        atomicAdd(&cnt[d.x], 1);
        atomicAdd(&cnt[d.y], 1);
        atomicAdd(&cnt[d.z], 1);
        atomicAdd(&cnt[d.w], 1);
    }
}

// Single-block (1024 thr) exclusive scan over cnt -> rowptr; dis[i] = 1/sqrt(cnt[i]+1)
__global__ __launch_bounds__(1024) void k_scan(const int* __restrict__ cnt,
                                               int* __restrict__ rowptr,
                                               float* __restrict__ dis) {
    __shared__ int s[1024];
    int t = threadIdx.x;
    const int CH = 16;  // 625 * 16 = 10000 exactly; threads 625..1023 idle
    int beg = t * CH;
    bool active = beg < N_NODES;
    int vals[CH];
    int sum = 0;
    if (active) {
        const int4* cp = (const int4*)(cnt + beg);
#pragma unroll
        for (int v = 0; v < CH / 4; ++v) {
            int4 q = cp[v];
            vals[4 * v + 0] = q.x;
            vals[4 * v + 1] = q.y;
            vals[4 * v + 2] = q.z;
            vals[4 * v + 3] = q.w;
        }
#pragma unroll
        for (int i = 0; i < CH; ++i) sum += vals[i];
    }
    s[t] = sum;
    __syncthreads();
    for (int off = 1; off < 1024; off <<= 1) {
        int v = (t >= off) ? s[t - off] : 0;
        __syncthreads();
        s[t] += v;
        __syncthreads();
    }
    if (active) {
        int run = s[t] - sum;
        int rp[CH];
        float dv[CH];
#pragma unroll
        for (int i = 0; i < CH; ++i) {
            rp[i] = run;
            int c = vals[i];
            dv[i] = rsqrtf((float)(c + 1));  // +1 for self-loop
            run += c;
        }
        int4* rpp = (int4*)(rowptr + beg);
        float4* dp = (float4*)(dis + beg);
#pragma unroll
        for (int v = 0; v < CH / 4; ++v) {
            rpp[v] = make_int4(rp[4 * v], rp[4 * v + 1], rp[4 * v + 2], rp[4 * v + 3]);
            dp[v] = make_float4(dv[4 * v], dv[4 * v + 1], dv[4 * v + 2], dv[4 * v + 3]);
        }
    }
    if (t == 1023) rowptr[N_NODES] = s[1023];
}

// ---------------- merged: CSR fill (blocks 0..1249) + GEMM1 (blocks 1250..1874)
// Both depend only on k_scan; disjoint resources (atomics vs LDS/VALU).
// GEMM1: y = dis[i] * (concat(obs,act) @ W)  [10000x34 @ 34x128]

__global__ __launch_bounds__(256) void k_fill_gemm1(
    const int* __restrict__ src, const int* __restrict__ dst,
    const int* __restrict__ rowptr, int* __restrict__ fill, int* __restrict__ col,
    const float* __restrict__ obs, const float* __restrict__ act,
    const float* __restrict__ W, const float* __restrict__ dis,
    float* __restrict__ y) {
    __shared__ float xs[16 * 34];
    __shared__ float ws[34 * 128];
    int bid = blockIdx.x;
    int t = threadIdx.x;
    if (bid < 1250) {  // 1250*256 = 320000 edges exactly
        int e = bid * 256 + t;
        int d = dst[e];
        int p = atomicAdd(&fill[d], 1);
        col[rowptr[d] + p] = src[e];
        return;
    }
    int row0 = (bid - 1250) * 16;  // 625 * 16 = 10000
    for (int i = t; i < 16 * 34; i += 256) {
        int r = i / 34, k = i % 34;
        int row = row0 + r;
        xs[i] = (k < OBS_DIM) ? obs[row * OBS_DIM + k]
                              : act[row * ACT_DIM + (k - OBS_DIM)];
    }
    {
        float4* wsp = (float4*)ws;
        const float4* Wp = (const float4*)W;
        for (int i = t; i < 34 * 128 / 4; i += 256) wsp[i] = Wp[i];
    }
    __syncthreads();
    int c = t & 127, half = t >> 7;
    float acc[8] = {0, 0, 0, 0, 0, 0, 0, 0};
    for (int k = 0; k < 34; ++k) {
        float wv = ws[k * 128 + c];
#pragma unroll
        for (int r = 0; r < 8; ++r) acc[r] += xs[(half * 8 + r) * 34 + k] * wv;
    }
#pragma unroll
    for (int r = 0; r < 8; ++r) {
        int row = row0 + half * 8 + r;
        y[row * HID + c] = dis[row] * acc[r];
    }
}

// ---------------- aggregation: out[i] = relu(dis[i]*(sum_{j in N(i)} y[j] + y[i]) + b)
// 1 wave per node, 8-deep gather unroll, dual accumulators.

__global__ __launch_bounds__(256) void k_agg(const float2* __restrict__ y,
                                             const int* __restrict__ rowptr,
                                             const int* __restrict__ col,
                                             const float* __restrict__ dis,
                                             const float2* __restrict__ bias,
                                             float2* __restrict__ out) {
    int t = threadIdx.x;
    int wave = t >> 6, lane = t & 63;
    int node = blockIdx.x * 4 + wave;
    if (node >= N_NODES) return;
    int beg = rowptr[node], end = rowptr[node + 1];
    float2 a = y[node * 64 + lane];
    float2 a2 = make_float2(0.0f, 0.0f);
    int e = beg;
    for (; e + 8 <= end; e += 8) {
        int j0 = col[e], j1 = col[e + 1], j2 = col[e + 2], j3 = col[e + 3];
        int j4 = col[e + 4], j5 = col[e + 5], j6 = col[e + 6], j7 = col[e + 7];
        float2 v0 = y[j0 * 64 + lane];
        float2 v1 = y[j1 * 64 + lane];
        float2 v2 = y[j2 * 64 + lane];
        float2 v3 = y[j3 * 64 + lane];
        float2 v4 = y[j4 * 64 + lane];
        float2 v5 = y[j5 * 64 + lane];
        float2 v6 = y[j6 * 64 + lane];
        float2 v7 = y[j7 * 64 + lane];
        a.x += (v0.x + v1.x) + (v2.x + v3.x);
        a.y += (v0.y + v1.y) + (v2.y + v3.y);
        a2.x += (v4.x + v5.x) + (v6.x + v7.x);
        a2.y += (v4.y + v5.y) + (v6.y + v7.y);
    }
    for (; e + 2 <= end; e += 2) {
        int j0 = col[e], j1 = col[e + 1];
        float2 v0 = y[j0 * 64 + lane];
        float2 v1 = y[j1 * 64 + lane];
        a.x += v0.x + v1.x;
        a.y += v0.y + v1.y;
    }
    if (e < end) {
        float2 v = y[col[e] * 64 + lane];
        a.x += v.x;
        a.y += v.y;
    }
    a.x += a2.x;
    a.y += a2.y;
    float di = dis[node];
    float2 b = bias[lane];
    float2 r;
    r.x = fmaxf(di * a.x + b.x, 0.0f);
    r.y = fmaxf(di * a.y + b.y, 0.0f);
    out[node * 64 + lane] = r;
}

// ---------------- GEMM128: y = dis[i] * (x @ W)  [10000x128 @ 128x128]

__global__ __launch_bounds__(256) void k_gemm128(const float* __restrict__ x,
                                                 const float* __restrict__ W,
                                                 const float* __restrict__ dis,
                                                 float* __restrict__ y) {
    __shared__ float xs[16 * 128];
    __shared__ float ws[32 * 128];
    int t = threadIdx.x;
    int row0 = blockIdx.x * 16;
    {
        float4* xsp = (float4*)xs;
        const float4* xp = (const float4*)(x + row0 * 128);
        for (int i = t; i < 512; i += 256) xsp[i] = xp[i];
    }
    int c = t & 127, half = t >> 7;
    float acc[8] = {0, 0, 0, 0, 0, 0, 0, 0};
    for (int ch = 0; ch < 4; ++ch) {
        __syncthreads();
        {
            float4* wsp = (float4*)ws;
            const float4* Wp = (const float4*)(W + ch * 4096);
            for (int i = t; i < 1024; i += 256) wsp[i] = Wp[i];
        }
        __syncthreads();
        for (int k = 0; k < 32; ++k) {
            float wv = ws[k * 128 + c];
#pragma unroll
            for (int r = 0; r < 8; ++r)
                acc[r] += xs[(half * 8 + r) * 128 + ch * 32 + k] * wv;
        }
    }
#pragma unroll
    for (int r = 0; r < 8; ++r) {
        int row = row0 + half * 8 + r;
        y[row * 128 + c] = dis[row] * acc[r];
    }
}

// ---------------- fused heads: q = relu(x@Wa + Ba) @ wb + bb  (both heads)

__global__ __launch_bounds__(256) void k_heads(const float* __restrict__ x,
                                               const float* __restrict__ W1, const float* __restrict__ B1,
                                               const float* __restrict__ w1b, const float* __restrict__ b1b,
                                               const float* __restrict__ W2, const float* __restrict__ B2,
                                               const float* __restrict__ w2b, const float* __restrict__ b2b,
                                               float* __restrict__ q1, float* __restrict__ q2) {
    __shared__ float xs[16 * 128];
    __shared__ float w1s[32 * 128];
    __shared__ float w2s[32 * 128];
    __shared__ float part1[4][8];
    __shared__ float part2[4][8];
    int t = threadIdx.x;
    int row0 = blockIdx.x * 16;
    {
        float4* xsp = (float4*)xs;
        const float4* xp = (const float4*)(x + row0 * 128);
        for (int i = t; i < 512; i += 256) xsp[i] = xp[i];
    }
    int c = t & 127, half = t >> 7;
    float a1[8] = {0, 0, 0, 0, 0, 0, 0, 0};
    float a2[8] = {0, 0, 0, 0, 0, 0, 0, 0};
    for (int ch = 0; ch < 4; ++ch) {
        __syncthreads();
        {
            float4* w1p = (float4*)w1s;
            float4* w2p = (float4*)w2s;
            const float4* W1p = (const float4*)(W1 + ch * 4096);
            const float4* W2p = (const float4*)(W2 + ch * 4096);
            for (int i = t; i < 1024; i += 256) {
                w1p[i] = W1p[i];
                w2p[i] = W2p[i];
            }
        }
        __syncthreads();
        for (int k = 0; k < 32; ++k) {
            float wv1 = w1s[k * 128 + c];
            float wv2 = w2s[k * 128 + c];
#pragma unroll
            for (int r = 0; r < 8; ++r) {
                float xv = xs[(half * 8 + r) * 128 + ch * 32 + k];
                a1[r] += xv * wv1;
                a2[r] += xv * wv2;
            }
        }
    }
    float bb1 = B1[c], bb2 = B2[c];
    float v1 = w1b[c], v2 = w2b[c];
    float s1[8], s2[8];
#pragma unroll
    for (int r = 0; r < 8; ++r) {
        float h1 = fmaxf(a1[r] + bb1, 0.0f);
        float h2 = fmaxf(a2[r] + bb2, 0.0f);
        s1[r] = h1 * v1;
        s2[r] = h2 * v2;
    }
#pragma unroll
    for (int off = 1; off < 64; off <<= 1) {
#pragma unroll
        for (int r = 0; r < 8; ++r) {
            s1[r] += __shfl_xor(s1[r], off);
            s2[r] += __shfl_xor(s2[r], off);
        }
    }
    int wave = t >> 6, lane = t & 63;
    if (lane == 0) {
#pragma unroll
        for (int r = 0; r < 8; ++r) {
            part1[wave][r] = s1[r];
            part2[wave][r] = s2[r];
        }
    }
    __syncthreads();
    if (t < 16) {
        int hf = t >> 3, r = t & 7;
        int row = row0 + hf * 8 + r;
        q1[row] = part1[hf * 2][r] + part1[hf * 2 + 1][r] + b1b[0];
        q2[row] = part2[hf * 2][r] + part2[hf * 2 + 1][r] + b2b[0];
    }
}

extern "C" void kernel_launch(void* const* d_in, const int* in_sizes, int n_in,
                              void* d_out, int out_size, void* d_ws, size_t ws_size,
                              hipStream_t stream) {
    (void)in_sizes; (void)n_in; (void)out_size; (void)ws_size;
    const float* obs  = (const float*)d_in[0];
    const float* act  = (const float*)d_in[1];
    const int*   ei   = (const int*)d_in[2];
    const int*   src  = ei;
    const int*   dst  = ei + N_EDGES;
    const float* w_g1 = (const float*)d_in[3];
    const float* b_g1 = (const float*)d_in[4];
    const float* w_g2 = (const float*)d_in[5];
    const float* b_g2 = (const float*)d_in[6];
    const float* w_q1a = (const float*)d_in[7];
    const float* b_q1a = (const float*)d_in[8];
    const float* w_q1b = (const float*)d_in[9];
    const float* b_q1b = (const float*)d_in[10];
    const float* w_q2a = (const float*)d_in[11];
    const float* b_q2a = (const float*)d_in[12];
    const float* w_q2b = (const float*)d_in[13];
    const float* b_q2b = (const float*)d_in[14];
    float* out = (float*)d_out;

    char* ws = (char*)d_ws;
    size_t off = 0;
    auto alloc = [&](size_t bytes) {
        void* p = ws + off;
        off = (off + bytes + 255) & ~(size_t)255;
        return p;
    };
    int*   cnt    = (int*)alloc(N_NODES * 4);
    int*   fill   = (int*)alloc(N_NODES * 4);
    int*   rowptr = (int*)alloc((N_NODES + 1) * 4);
    float* dis    = (float*)alloc(N_NODES * 4);
    int*   col    = (int*)alloc((size_t)N_EDGES * 4);
    float* buf0   = (float*)alloc((size_t)N_NODES * HID * 4);
    float* buf1   = (float*)alloc((size_t)N_NODES * HID * 4);

    k_zero<<<(N_NODES + 255) / 256, 256, 0, stream>>>(cnt, fill);
    k_hist<<<(N_EDGES / 4 + 255) / 256, 256, 0, stream>>>((const int4*)dst, cnt);
    k_scan<<<1, 1024, 0, stream>>>(cnt, rowptr, dis);
    k_fill_gemm1<<<1875, 256, 0, stream>>>(src, dst, rowptr, fill, col,
                                           obs, act, w_g1, dis, buf0);
    k_agg<<<2500, 256, 0, stream>>>((const float2*)buf0, rowptr, col, dis,
                                    (const float2*)b_g1, (float2*)buf1);
    k_gemm128<<<625, 256, 0, stream>>>(buf1, w_g2, dis, buf0);
    k_agg<<<2500, 256, 0, stream>>>((const float2*)buf0, rowptr, col, dis,
                                    (const float2*)b_g2, (float2*)buf1);
    k_heads<<<625, 256, 0, stream>>>(buf1, w_q1a, b_q1a, w_q1b, b_q1b,
                                     w_q2a, b_q2a, w_q2b, b_q2b,
                                     out, out + N_NODES);
}

// Round 5
// 122.990 us; speedup vs baseline: 3.0222x; 1.1768x over previous
//
#include <hip/hip_runtime.h>

#define N_NODES 10000
#define N_EDGES 320000
#define OBS_DIM 30
#define ACT_DIM 4
#define HID 128
#define ELL_W 96  // padded neighbor-list width; deg ~Poisson(32), P(deg>88) ~ 1e-12

// ---------------- init: cnt=0, col=sentinel(N_NODES), y[N_NODES] row = 0 ----------------

__global__ __launch_bounds__(256) void k_init(int* __restrict__ cnt,
                                              int* __restrict__ col,
                                              float* __restrict__ ysent) {
    int i = blockIdx.x * 256 + threadIdx.x;
    if (i < N_NODES * ELL_W / 4)
        ((int4*)col)[i] = make_int4(N_NODES, N_NODES, N_NODES, N_NODES);
    if (i < N_NODES / 4)
        ((int4*)cnt)[i] = make_int4(0, 0, 0, 0);
    if (i < HID / 4)
        ((float4*)ysent)[i] = make_float4(0.f, 0.f, 0.f, 0.f);
}

// ---------------- build: one atomic per edge reserves slot AND counts degree ----------------

__global__ __launch_bounds__(256) void k_build(const int4* __restrict__ src4,
                                               const int4* __restrict__ dst4,
                                               int* __restrict__ cnt,
                                               int* __restrict__ col) {
    int i = blockIdx.x * 256 + threadIdx.x;
    if (i < N_EDGES / 4) {
        int4 s = src4[i];
        int4 d = dst4[i];
        int p;
        p = atomicAdd(&cnt[d.x], 1); col[d.x * ELL_W + p] = s.x;
        p = atomicAdd(&cnt[d.y], 1); col[d.y * ELL_W + p] = s.y;
        p = atomicAdd(&cnt[d.z], 1); col[d.z * ELL_W + p] = s.z;
        p = atomicAdd(&cnt[d.w], 1); col[d.w * ELL_W + p] = s.w;
    }
}

// ---------------- GEMM1: y = dis[i]*(concat(obs,act)@W); also stores dis[i]=rsqrt(cnt+1)

__global__ __launch_bounds__(256) void k_gemm1(const float* __restrict__ obs,
                                               const float* __restrict__ act,
                                               const float* __restrict__ W,
                                               const int* __restrict__ cnt,
                                               float* __restrict__ dis,
                                               float* __restrict__ y) {
    __shared__ float xs[16 * 34];
    __shared__ float ws[34 * 128];
    int t = threadIdx.x;
    int row0 = blockIdx.x * 16;  // 625 * 16 = 10000
    for (int i = t; i < 16 * 34; i += 256) {
        int r = i / 34, k = i % 34;
        int row = row0 + r;
        xs[i] = (k < OBS_DIM) ? obs[row * OBS_DIM + k]
                              : act[row * ACT_DIM + (k - OBS_DIM)];
    }
    {
        float4* wsp = (float4*)ws;
        const float4* Wp = (const float4*)W;
        for (int i = t; i < 34 * 128 / 4; i += 256) wsp[i] = Wp[i];
    }
    __syncthreads();
    int c = t & 127, half = t >> 7;
    float acc[8] = {0, 0, 0, 0, 0, 0, 0, 0};
    for (int k = 0; k < 34; ++k) {
        float wv = ws[k * 128 + c];
#pragma unroll
        for (int r = 0; r < 8; ++r) acc[r] += xs[(half * 8 + r) * 34 + k] * wv;
    }
#pragma unroll
    for (int r = 0; r < 8; ++r) {
        int row = row0 + half * 8 + r;
        float d = rsqrtf((float)(cnt[row] + 1));
        y[row * HID + c] = d * acc[r];
        if (c == 0) dis[row] = d;
    }
}

// ---------------- aggregation: out[i] = relu(dis[i]*(sum_N y[j] + y[i]) + b)
// 1 wave/node; 32 lanes x float4 per row; 2 rows per VMEM instr; sentinel-padded, no tails.

__global__ __launch_bounds__(256) void k_agg(const float4* __restrict__ y4,
                                             const int* __restrict__ cnt,
                                             const int* __restrict__ col,
                                             const float* __restrict__ dis,
                                             const float4* __restrict__ bias4,
                                             float4* __restrict__ out4) {
    int t = threadIdx.x;
    int wave = t >> 6, lane = t & 63, half = lane >> 5, sub = lane & 31;
    int node = blockIdx.x * 4 + wave;
    if (node >= N_NODES) return;
    int deg = cnt[node];
    const int* cp = col + node * ELL_W;
    float4 a = make_float4(0.f, 0.f, 0.f, 0.f);
    if (!half) a = y4[node * 32 + sub];  // self-loop term
    for (int e = 0; e < deg; e += 8) {
        int j0 = cp[e + half];
        int j1 = cp[e + 2 + half];
        int j2 = cp[e + 4 + half];
        int j3 = cp[e + 6 + half];
        float4 v0 = y4[j0 * 32 + sub];
        float4 v1 = y4[j1 * 32 + sub];
        float4 v2 = y4[j2 * 32 + sub];
        float4 v3 = y4[j3 * 32 + sub];
        a.x += (v0.x + v1.x) + (v2.x + v3.x);
        a.y += (v0.y + v1.y) + (v2.y + v3.y);
        a.z += (v0.z + v1.z) + (v2.z + v3.z);
        a.w += (v0.w + v1.w) + (v2.w + v3.w);
    }
    a.x += __shfl_xor(a.x, 32);
    a.y += __shfl_xor(a.y, 32);
    a.z += __shfl_xor(a.z, 32);
    a.w += __shfl_xor(a.w, 32);
    if (!half) {
        float dn = dis[node];
        float4 b = bias4[sub];
        float4 r;
        r.x = fmaxf(dn * a.x + b.x, 0.0f);
        r.y = fmaxf(dn * a.y + b.y, 0.0f);
        r.z = fmaxf(dn * a.z + b.z, 0.0f);
        r.w = fmaxf(dn * a.w + b.w, 0.0f);
        out4[node * 32 + sub] = r;
    }
}

// ---------------- GEMM128: y = dis[i] * (x @ W)  [10000x128 @ 128x128]

__global__ __launch_bounds__(256) void k_gemm128(const float* __restrict__ x,
                                                 const float* __restrict__ W,
                                                 const float* __restrict__ dis,
                                                 float* __restrict__ y) {
    __shared__ float xs[16 * 128];
    __shared__ float ws[32 * 128];
    int t = threadIdx.x;
    int row0 = blockIdx.x * 16;
    {
        float4* xsp = (float4*)xs;
        const float4* xp = (const float4*)(x + row0 * 128);
        for (int i = t; i < 512; i += 256) xsp[i] = xp[i];
    }
    int c = t & 127, half = t >> 7;
    float acc[8] = {0, 0, 0, 0, 0, 0, 0, 0};
    for (int ch = 0; ch < 4; ++ch) {
        __syncthreads();
        {
            float4* wsp = (float4*)ws;
            const float4* Wp = (const float4*)(W + ch * 4096);
            for (int i = t; i < 1024; i += 256) wsp[i] = Wp[i];
        }
        __syncthreads();
        for (int k = 0; k < 32; ++k) {
            float wv = ws[k * 128 + c];
#pragma unroll
            for (int r = 0; r < 8; ++r)
                acc[r] += xs[(half * 8 + r) * 128 + ch * 32 + k] * wv;
        }
    }
#pragma unroll
    for (int r = 0; r < 8; ++r) {
        int row = row0 + half * 8 + r;
        y[row * 128 + c] = dis[row] * acc[r];
    }
}

// ---------------- fused heads: q = relu(x@Wa + Ba) @ wb + bb  (both heads)

__global__ __launch_bounds__(256) void k_heads(const float* __restrict__ x,
                                               const float* __restrict__ W1, const float* __restrict__ B1,
                                               const float* __restrict__ w1b, const float* __restrict__ b1b,
                                               const float* __restrict__ W2, const float* __restrict__ B2,
                                               const float* __restrict__ w2b, const float* __restrict__ b2b,
                                               float* __restrict__ q1, float* __restrict__ q2) {
    __shared__ float xs[16 * 128];
    __shared__ float w1s[32 * 128];
    __shared__ float w2s[32 * 128];
    __shared__ float part1[4][8];
    __shared__ float part2[4][8];
    int t = threadIdx.x;
    int row0 = blockIdx.x * 16;
    {
        float4* xsp = (float4*)xs;
        const float4* xp = (const float4*)(x + row0 * 128);
        for (int i = t; i < 512; i += 256) xsp[i] = xp[i];
    }
    int c = t & 127, half = t >> 7;
    float a1[8] = {0, 0, 0, 0, 0, 0, 0, 0};
    float a2[8] = {0, 0, 0, 0, 0, 0, 0, 0};
    for (int ch = 0; ch < 4; ++ch) {
        __syncthreads();
        {
            float4* w1p = (float4*)w1s;
            float4* w2p = (float4*)w2s;
            const float4* W1p = (const float4*)(W1 + ch * 4096);
            const float4* W2p = (const float4*)(W2 + ch * 4096);
            for (int i = t; i < 1024; i += 256) {
                w1p[i] = W1p[i];
                w2p[i] = W2p[i];
            }
        }
        __syncthreads();
        for (int k = 0; k < 32; ++k) {
            float wv1 = w1s[k * 128 + c];
            float wv2 = w2s[k * 128 + c];
#pragma unroll
            for (int r = 0; r < 8; ++r) {
                float xv = xs[(half * 8 + r) * 128 + ch * 32 + k];
                a1[r] += xv * wv1;
                a2[r] += xv * wv2;
            }
        }
    }
    float bb1 = B1[c], bb2 = B2[c];
    float v1 = w1b[c], v2 = w2b[c];
    float s1[8], s2[8];
#pragma unroll
    for (int r = 0; r < 8; ++r) {
        float h1 = fmaxf(a1[r] + bb1, 0.0f);
        float h2 = fmaxf(a2[r] + bb2, 0.0f);
        s1[r] = h1 * v1;
        s2[r] = h2 * v2;
    }
#pragma unroll
    for (int off = 1; off < 64; off <<= 1) {
#pragma unroll
        for (int r = 0; r < 8; ++r) {
            s1[r] += __shfl_xor(s1[r], off);
            s2[r] += __shfl_xor(s2[r], off);
        }
    }
    int wave = t >> 6, lane = t & 63;
    if (lane == 0) {
#pragma unroll
        for (int r = 0; r < 8; ++r) {
            part1[wave][r] = s1[r];
            part2[wave][r] = s2[r];
        }
    }
    __syncthreads();
    if (t < 16) {
        int hf = t >> 3, r = t & 7;
        int row = row0 + hf * 8 + r;
        q1[row] = part1[hf * 2][r] + part1[hf * 2 + 1][r] + b1b[0];
        q2[row] = part2[hf * 2][r] + part2[hf * 2 + 1][r] + b2b[0];
    }
}

extern "C" void kernel_launch(void* const* d_in, const int* in_sizes, int n_in,
                              void* d_out, int out_size, void* d_ws, size_t ws_size,
                              hipStream_t stream) {
    (void)in_sizes; (void)n_in; (void)out_size; (void)ws_size;
    const float* obs  = (const float*)d_in[0];
    const float* act  = (const float*)d_in[1];
    const int*   ei   = (const int*)d_in[2];
    const int*   src  = ei;
    const int*   dst  = ei + N_EDGES;
    const float* w_g1 = (const float*)d_in[3];
    const float* b_g1 = (const float*)d_in[4];
    const float* w_g2 = (const float*)d_in[5];
    const float* b_g2 = (const float*)d_in[6];
    const float* w_q1a = (const float*)d_in[7];
    const float* b_q1a = (const float*)d_in[8];
    const float* w_q1b = (const float*)d_in[9];
    const float* b_q1b = (const float*)d_in[10];
    const float* w_q2a = (const float*)d_in[11];
    const float* b_q2a = (const float*)d_in[12];
    const float* w_q2b = (const float*)d_in[13];
    const float* b_q2b = (const float*)d_in[14];
    float* out = (float*)d_out;

    char* ws = (char*)d_ws;
    size_t off = 0;
    auto alloc = [&](size_t bytes) {
        void* p = ws + off;
        off = (off + bytes + 255) & ~(size_t)255;
        return p;
    };
    int*   cnt  = (int*)alloc(N_NODES * 4);
    float* dis  = (float*)alloc(N_NODES * 4);
    int*   col  = (int*)alloc((size_t)N_NODES * ELL_W * 4);
    float* buf0 = (float*)alloc((size_t)(N_NODES + 1) * HID * 4);  // +1 sentinel row
    float* buf1 = (float*)alloc((size_t)N_NODES * HID * 4);

    float* ysent = buf0 + (size_t)N_NODES * HID;

    k_init<<<(N_NODES * ELL_W / 4 + 255) / 256, 256, 0, stream>>>(cnt, col, ysent);
    k_build<<<(N_EDGES / 4 + 255) / 256, 256, 0, stream>>>(
        (const int4*)src, (const int4*)dst, cnt, col);

    k_gemm1<<<625, 256, 0, stream>>>(obs, act, w_g1, cnt, dis, buf0);
    k_agg<<<2500, 256, 0, stream>>>((const float4*)buf0, cnt, col, dis,
                                    (const float4*)b_g1, (float4*)buf1);
    k_gemm128<<<625, 256, 0, stream>>>(buf1, w_g2, dis, buf0);
    k_agg<<<2500, 256, 0, stream>>>((const float4*)buf0, cnt, col, dis,
                                    (const float4*)b_g2, (float4*)buf1);
    k_heads<<<625, 256, 0, stream>>>(buf1, w_q1a, b_q1a, w_q1b, b_q1b,
                                     w_q2a, b_q2a, w_q2b, b_q2b,
                                     out, out + N_NODES);
}

// Round 6
// 107.791 us; speedup vs baseline: 3.4484x; 1.1410x over previous
//
#include <hip/hip_runtime.h>

#define N_NODES 10000
#define N_EDGES 320000
#define OBS_DIM 30
#define ACT_DIM 4
#define HID 128
#define ELL_W 96   // padded neighbor-list width; deg ~Poisson(32), P(deg>88) ~ 1e-12
#define SENT N_NODES

// ---------------- init: cnt[0..N]=0, xpad rows (obs|act|0) + zero sentinel row,
//                  y2 sentinel row = 0 ----------------

__global__ __launch_bounds__(256) void k_init(int* __restrict__ cnt,
                                              float* __restrict__ xpad,
                                              float* __restrict__ y2,  // buf0, row SENT zeroed
                                              const float* __restrict__ obs,
                                              const float* __restrict__ act) {
    int i = blockIdx.x * 256 + threadIdx.x;
    // xpad: (N_NODES+1) rows x 16 float4 (64 floats; [0..29]=obs, [30..33]=act, rest 0)
    if (i < (N_NODES + 1) * 16) {
        int row = i >> 4, sub = i & 15;
        float4 v = make_float4(0.f, 0.f, 0.f, 0.f);
        if (row < N_NODES) {
            float* vv = &v.x;
#pragma unroll
            for (int k = 0; k < 4; ++k) {
                int c = sub * 4 + k;
                if (c < OBS_DIM) vv[k] = obs[row * OBS_DIM + c];
                else if (c < OBS_DIM + ACT_DIM) vv[k] = act[row * ACT_DIM + (c - OBS_DIM)];
            }
        }
        ((float4*)xpad)[i] = v;
    }
    if (i <= N_NODES) cnt[i] = 0;
    if (i < HID / 4)
        ((float4*)(y2 + (size_t)SENT * HID))[i] = make_float4(0.f, 0.f, 0.f, 0.f);
}

// ---------------- build: one atomic per edge reserves ELL slot AND counts degree ----------------

__global__ __launch_bounds__(256) void k_build(const int4* __restrict__ src4,
                                               const int4* __restrict__ dst4,
                                               int* __restrict__ cnt,
                                               int* __restrict__ col) {
    int i = blockIdx.x * 256 + threadIdx.x;
    if (i < N_EDGES / 4) {
        int4 s = src4[i];
        int4 d = dst4[i];
        int p;
        p = atomicAdd(&cnt[d.x], 1); col[d.x * ELL_W + p] = s.x;
        p = atomicAdd(&cnt[d.y], 1); col[d.y * ELL_W + p] = s.y;
        p = atomicAdd(&cnt[d.z], 1); col[d.z * ELL_W + p] = s.z;
        p = atomicAdd(&cnt[d.w], 1); col[d.w * ELL_W + p] = s.w;
    }
}

// ---------------- fused layer-1: z_i = d_i*(sum_j d_j*x_j + d_i*x_i)  (34-dim gather)
//                  h1_i = relu(z_i @ W1 + b1)   [per-wave epilogue, W1 in LDS]
// 8 waves/block, 1 node/wave; 16 lanes x float4 per row, 8 rows in flight.

__global__ __launch_bounds__(512) void k_agg1_gemm1(const float4* __restrict__ x4,
                                                    const int* __restrict__ cnt,
                                                    const int* __restrict__ col,
                                                    const float* __restrict__ W1,
                                                    const float* __restrict__ b1,
                                                    float* __restrict__ dis,
                                                    float* __restrict__ h1) {
    __shared__ float ws[34 * 128];
    __shared__ float zs[8][64];
    int t = threadIdx.x;
    {
        float4* wsp = (float4*)ws;
        const float4* Wp = (const float4*)W1;
        for (int i = t; i < 34 * 128 / 4; i += 512) wsp[i] = Wp[i];
    }
    __syncthreads();
    int wave = t >> 6, lane = t & 63, g = lane >> 4, sub = lane & 15;
    int node = blockIdx.x * 8 + wave;  // 1250*8 = 10000 exactly
    int deg = cnt[node];
    float di = rsqrtf((float)(deg + 1));
    const int* cp = col + node * ELL_W;
    float4 a = make_float4(0.f, 0.f, 0.f, 0.f);
    if (g == 0) {
        float4 xv = x4[node * 16 + sub];
        a.x = di * xv.x; a.y = di * xv.y; a.z = di * xv.z; a.w = di * xv.w;
    }
    for (int e = 0; e < deg; e += 8) {
        int s0 = e + g, s1 = e + 4 + g;
        int j0 = (s0 < deg) ? cp[s0] : SENT;  // cnt[SENT]=0 -> d=1, x=0 -> +0
        int j1 = (s1 < deg) ? cp[s1] : SENT;
        float d0 = rsqrtf((float)(cnt[j0] + 1));
        float d1 = rsqrtf((float)(cnt[j1] + 1));
        float4 v0 = x4[j0 * 16 + sub];
        float4 v1 = x4[j1 * 16 + sub];
        a.x += d0 * v0.x + d1 * v1.x;
        a.y += d0 * v0.y + d1 * v1.y;
        a.z += d0 * v0.z + d1 * v1.z;
        a.w += d0 * v0.w + d1 * v1.w;
    }
    // reduce across the 4 sixteen-lane groups
    a.x += __shfl_xor(a.x, 16); a.x += __shfl_xor(a.x, 32);
    a.y += __shfl_xor(a.y, 16); a.y += __shfl_xor(a.y, 32);
    a.z += __shfl_xor(a.z, 16); a.z += __shfl_xor(a.z, 32);
    a.w += __shfl_xor(a.w, 16); a.w += __shfl_xor(a.w, 32);
    if (g == 0) {
        float4 z;
        z.x = di * a.x; z.y = di * a.y; z.z = di * a.z; z.w = di * a.w;
        *(float4*)&zs[wave][sub * 4] = z;
    }
    if (lane == 0) dis[node] = di;
    // per-wave mini-GEMM: h1[node][c] for c = lane, lane+64  (no barrier needed:
    // zs[wave] written and read by the same wave; compiler inserts lgkmcnt)
    float h0 = b1[lane], h64 = b1[lane + 64];
#pragma unroll
    for (int k = 0; k < 34; ++k) {
        float zk = zs[wave][k];
        h0 += zk * ws[k * 128 + lane];
        h64 += zk * ws[k * 128 + 64 + lane];
    }
    h1[node * HID + lane] = fmaxf(h0, 0.0f);
    h1[node * HID + 64 + lane] = fmaxf(h64, 0.0f);
}

// ---------------- GEMM128: y2 = dis[i] * (h1 @ W2)  [10000x128 @ 128x128]

__global__ __launch_bounds__(256) void k_gemm128(const float* __restrict__ x,
                                                 const float* __restrict__ W,
                                                 const float* __restrict__ dis,
                                                 float* __restrict__ y) {
    __shared__ float xs[16 * 128];
    __shared__ float ws[32 * 128];
    int t = threadIdx.x;
    int row0 = blockIdx.x * 16;
    {
        float4* xsp = (float4*)xs;
        const float4* xp = (const float4*)(x + row0 * 128);
        for (int i = t; i < 512; i += 256) xsp[i] = xp[i];
    }
    int c = t & 127, half = t >> 7;
    float acc[8] = {0, 0, 0, 0, 0, 0, 0, 0};
    for (int ch = 0; ch < 4; ++ch) {
        __syncthreads();
        {
            float4* wsp = (float4*)ws;
            const float4* Wp = (const float4*)(W + ch * 4096);
            for (int i = t; i < 1024; i += 256) wsp[i] = Wp[i];
        }
        __syncthreads();
        for (int k = 0; k < 32; ++k) {
            float wv = ws[k * 128 + c];
#pragma unroll
            for (int r = 0; r < 8; ++r)
                acc[r] += xs[(half * 8 + r) * 128 + ch * 32 + k] * wv;
        }
    }
#pragma unroll
    for (int r = 0; r < 8; ++r) {
        int row = row0 + half * 8 + r;
        y[row * 128 + c] = dis[row] * acc[r];
    }
}

// ---------------- aggregation 2: h2 = relu(dis_i*(sum_j y2_j + y2_i) + b2)
// 1 wave/node; 32 lanes x float4; 2 rows/VMEM instr; cndmask tails to sentinel row.

__global__ __launch_bounds__(256) void k_agg2(const float4* __restrict__ y4,
                                              const int* __restrict__ cnt,
                                              const int* __restrict__ col,
                                              const float* __restrict__ dis,
                                              const float4* __restrict__ bias4,
                                              float4* __restrict__ out4) {
    int t = threadIdx.x;
    int wave = t >> 6, lane = t & 63, half = lane >> 5, sub = lane & 31;
    int node = blockIdx.x * 4 + wave;
    if (node >= N_NODES) return;
    int deg = cnt[node];
    const int* cp = col + node * ELL_W;
    float4 a = make_float4(0.f, 0.f, 0.f, 0.f);
    if (!half) a = y4[node * 32 + sub];  // self-loop term
    for (int e = 0; e < deg; e += 8) {
        int s0 = e + half, s1 = e + 2 + half, s2 = e + 4 + half, s3 = e + 6 + half;
        int j0 = (s0 < deg) ? cp[s0] : SENT;  // y2[SENT] row = 0
        int j1 = (s1 < deg) ? cp[s1] : SENT;
        int j2 = (s2 < deg) ? cp[s2] : SENT;
        int j3 = (s3 < deg) ? cp[s3] : SENT;
        float4 v0 = y4[j0 * 32 + sub];
        float4 v1 = y4[j1 * 32 + sub];
        float4 v2 = y4[j2 * 32 + sub];
        float4 v3 = y4[j3 * 32 + sub];
        a.x += (v0.x + v1.x) + (v2.x + v3.x);
        a.y += (v0.y + v1.y) + (v2.y + v3.y);
        a.z += (v0.z + v1.z) + (v2.z + v3.z);
        a.w += (v0.w + v1.w) + (v2.w + v3.w);
    }
    a.x += __shfl_xor(a.x, 32);
    a.y += __shfl_xor(a.y, 32);
    a.z += __shfl_xor(a.z, 32);
    a.w += __shfl_xor(a.w, 32);
    if (!half) {
        float dn = dis[node];
        float4 b = bias4[sub];
        float4 r;
        r.x = fmaxf(dn * a.x + b.x, 0.0f);
        r.y = fmaxf(dn * a.y + b.y, 0.0f);
        r.z = fmaxf(dn * a.z + b.z, 0.0f);
        r.w = fmaxf(dn * a.w + b.w, 0.0f);
        out4[node * 32 + sub] = r;
    }
}

// ---------------- fused heads: q = relu(x@Wa + Ba) @ wb + bb  (both heads)

__global__ __launch_bounds__(256) void k_heads(const float* __restrict__ x,
                                               const float* __restrict__ W1, const float* __restrict__ B1,
                                               const float* __restrict__ w1b, const float* __restrict__ b1b,
                                               const float* __restrict__ W2, const float* __restrict__ B2,
                                               const float* __restrict__ w2b, const float* __restrict__ b2b,
                                               float* __restrict__ q1, float* __restrict__ q2) {
    __shared__ float xs[16 * 128];
    __shared__ float w1s[32 * 128];
    __shared__ float w2s[32 * 128];
    __shared__ float part1[4][8];
    __shared__ float part2[4][8];
    int t = threadIdx.x;
    int row0 = blockIdx.x * 16;
    {
        float4* xsp = (float4*)xs;
        const float4* xp = (const float4*)(x + row0 * 128);
        for (int i = t; i < 512; i += 256) xsp[i] = xp[i];
    }
    int c = t & 127, half = t >> 7;
    float a1[8] = {0, 0, 0, 0, 0, 0, 0, 0};
    float a2[8] = {0, 0, 0, 0, 0, 0, 0, 0};
    for (int ch = 0; ch < 4; ++ch) {
        __syncthreads();
        {
            float4* w1p = (float4*)w1s;
            float4* w2p = (float4*)w2s;
            const float4* W1p = (const float4*)(W1 + ch * 4096);
            const float4* W2p = (const float4*)(W2 + ch * 4096);
            for (int i = t; i < 1024; i += 256) {
                w1p[i] = W1p[i];
                w2p[i] = W2p[i];
            }
        }
        __syncthreads();
        for (int k = 0; k < 32; ++k) {
            float wv1 = w1s[k * 128 + c];
            float wv2 = w2s[k * 128 + c];
#pragma unroll
            for (int r = 0; r < 8; ++r) {
                float xv = xs[(half * 8 + r) * 128 + ch * 32 + k];
                a1[r] += xv * wv1;
                a2[r] += xv * wv2;
            }
        }
    }
    float bb1 = B1[c], bb2 = B2[c];
    float v1 = w1b[c], v2 = w2b[c];
    float s1[8], s2[8];
#pragma unroll
    for (int r = 0; r < 8; ++r) {
        float h1 = fmaxf(a1[r] + bb1, 0.0f);
        float h2 = fmaxf(a2[r] + bb2, 0.0f);
        s1[r] = h1 * v1;
        s2[r] = h2 * v2;
    }
#pragma unroll
    for (int off = 1; off < 64; off <<= 1) {
#pragma unroll
        for (int r = 0; r < 8; ++r) {
            s1[r] += __shfl_xor(s1[r], off);
            s2[r] += __shfl_xor(s2[r], off);
        }
    }
    int wave = t >> 6, lane = t & 63;
    if (lane == 0) {
#pragma unroll
        for (int r = 0; r < 8; ++r) {
            part1[wave][r] = s1[r];
            part2[wave][r] = s2[r];
        }
    }
    __syncthreads();
    if (t < 16) {
        int hf = t >> 3, r = t & 7;
        int row = row0 + hf * 8 + r;
        q1[row] = part1[hf * 2][r] + part1[hf * 2 + 1][r] + b1b[0];
        q2[row] = part2[hf * 2][r] + part2[hf * 2 + 1][r] + b2b[0];
    }
}

extern "C" void kernel_launch(void* const* d_in, const int* in_sizes, int n_in,
                              void* d_out, int out_size, void* d_ws, size_t ws_size,
                              hipStream_t stream) {
    (void)in_sizes; (void)n_in; (void)out_size; (void)ws_size;
    const float* obs  = (const float*)d_in[0];
    const float* act  = (const float*)d_in[1];
    const int*   ei   = (const int*)d_in[2];
    const int*   src  = ei;
    const int*   dst  = ei + N_EDGES;
    const float* w_g1 = (const float*)d_in[3];
    const float* b_g1 = (const float*)d_in[4];
    const float* w_g2 = (const float*)d_in[5];
    const float* b_g2 = (const float*)d_in[6];
    const float* w_q1a = (const float*)d_in[7];
    const float* b_q1a = (const float*)d_in[8];
    const float* w_q1b = (const float*)d_in[9];
    const float* b_q1b = (const float*)d_in[10];
    const float* w_q2a = (const float*)d_in[11];
    const float* b_q2a = (const float*)d_in[12];
    const float* w_q2b = (const float*)d_in[13];
    const float* b_q2b = (const float*)d_in[14];
    float* out = (float*)d_out;

    char* ws = (char*)d_ws;
    size_t off = 0;
    auto alloc = [&](size_t bytes) {
        void* p = ws + off;
        off = (off + bytes + 255) & ~(size_t)255;
        return p;
    };
    int*   cnt  = (int*)alloc((N_NODES + 1) * 4);
    float* dis  = (float*)alloc(N_NODES * 4);
    int*   col  = (int*)alloc((size_t)N_NODES * ELL_W * 4);
    float* xpad = (float*)alloc((size_t)(N_NODES + 1) * 64 * 4);
    float* h1b  = (float*)alloc((size_t)N_NODES * HID * 4);        // h1
    float* y2b  = (float*)alloc((size_t)(N_NODES + 1) * HID * 4);  // y2 (+sentinel row)
    float* h2b  = (float*)alloc((size_t)N_NODES * HID * 4);        // h2

    k_init<<<((N_NODES + 1) * 16 + 255) / 256, 256, 0, stream>>>(cnt, xpad, y2b, obs, act);
    k_build<<<(N_EDGES / 4 + 255) / 256, 256, 0, stream>>>(
        (const int4*)src, (const int4*)dst, cnt, col);

    k_agg1_gemm1<<<1250, 512, 0, stream>>>((const float4*)xpad, cnt, col,
                                           w_g1, b_g1, dis, h1b);
    k_gemm128<<<625, 256, 0, stream>>>(h1b, w_g2, dis, y2b);
    k_agg2<<<2500, 256, 0, stream>>>((const float4*)y2b, cnt, col, dis,
                                     (const float4*)b_g2, (float4*)h2b);
    k_heads<<<625, 256, 0, stream>>>(h2b, w_q1a, b_q1a, w_q1b, b_q1b,
                                     w_q2a, b_q2a, w_q2b, b_q2b,
                                     out, out + N_NODES);
}